// Round 2
// baseline (221.286 us; speedup 1.0000x reference)
//
#include <hip/hip_runtime.h>

// ---------------------------------------------------------------------------
// colorableGNN: 3x GCN(128->128) + FC(128->128) + FC(128->2) + mean-pool + softmax
// R16 (delta vs R15): scaled-H algebraic restructure.
//  - Store h' = invs*h (scaled at producer: X-conv and GEMM epilogue). Then
//    agg_j = invs_j*(sum h'_src + h'_self): per-edge weight ELIMINATED.
//  - epack records are 2B (src only), per-bucket fixed segments (SEGP=5120),
//    per-node lists padded to x8 with zero-row sentinel (row N) -> k_agg loads
//    8 edges with ONE uint4 (vmem issues/batch 16->9), no remainder branch.
//    indptr packs base(21b)|batches(10b) in one u32.
//  - deg[] via global atomics in k_bin; invs computed lazily (rsqrt(deg+1)).
//    k_binvs_bscan DELETED (no seg histogram, no bucket scan needed).
//    k_scatter drops its histogram pass (reads deg) and all invs work.
//  - sums/cnts/tdone zeroing folded into k_bin's W-prep block 0.
// NOTE: gather kernels need occupancy; never fuse agg into GEMM (R7: 104us).
// ---------------------------------------------------------------------------

#define CH 128
#define BSH 7              // 128 dst nodes per bucket
#define SEG 4096           // raw segment capacity (records) per bucket
#define SEGP 5120          // padded epack segment (ushort records) per bucket
#define EPW 4096           // edges per phase-1 workgroup
#define SAF 136            // LDS stride full-K tiles (shorts; 272B = 17*16B)
#define SC8 144            // fp8 epilogue stride (bytes)

typedef unsigned short ushortT;
typedef unsigned int uintT;
typedef unsigned char ucharT;
typedef __attribute__((ext_vector_type(8))) short short8;
typedef __attribute__((ext_vector_type(4))) float floatx4;
typedef __attribute__((ext_vector_type(2))) float floatx2;

__device__ __forceinline__ float bf2f(uintT u) {
    return __uint_as_float(u << 16);
}
__device__ __forceinline__ ushortT f2bf(float f) {
    uintT x = __float_as_uint(f);
    return (ushortT)((x + 0x7fffu + ((x >> 16) & 1u)) >> 16);
}
__device__ __forceinline__ void dec4(uintT u, float* o) {
    floatx2 lo = __builtin_amdgcn_cvt_pk_f32_fp8((int)u, false);
    floatx2 hi = __builtin_amdgcn_cvt_pk_f32_fp8((int)u, true);
    o[0] = lo.x; o[1] = lo.y; o[2] = hi.x; o[3] = hi.y;
}
__device__ __forceinline__ void dec16(uint4 v, float* o) {
    dec4(v.x, o); dec4(v.y, o + 4); dec4(v.z, o + 8); dec4(v.w, o + 12);
}

// ---- phase 1: bin edges into dst-buckets + global deg atomics -------------
// extra blocks past NBB do weight prep (+ block 0: zero sums/cnts/tdone)
__global__ __launch_bounds__(256) void k_bin(const int* __restrict__ row,
                                             const int* __restrict__ col,
                                             int* __restrict__ bfill,
                                             int* __restrict__ deg,
                                             uintT* __restrict__ seg,
                                             const float* __restrict__ w0,
                                             const float* __restrict__ w1,
                                             const float* __restrict__ w2,
                                             const float* __restrict__ w3,
                                             ushortT* __restrict__ Whi,
                                             float* __restrict__ sums,
                                             int* __restrict__ tdone,
                                             int E, int NBB, int NB, int G) {
    __shared__ uintT staged[EPW];   // 16 KB
    __shared__ int target[EPW];     // 16 KB
    __shared__ int sval[512];
    __shared__ int horig[512];
    __shared__ int pcnt[512];
    __shared__ int gbase[512];
    const int t = threadIdx.x;

    if ((int)blockIdx.x >= NBB) {
        // weight prep: transpose + bf16
        int bb = (int)blockIdx.x - NBB;
        int idx = bb * 256 + t;   // 0..65535
        int m = idx >> 14;
        int r2 = idx & 16383;
        int n = r2 >> 7;
        int k = r2 & 127;
        const float* W = (m == 0) ? w0 : (m == 1) ? w1 : (m == 2) ? w2 : w3;
        Whi[m * 16384 + n * CH + k] = f2bf(W[k * CH + n]);
        if (bb == 0) {
            if (t < 3 * G) sums[t] = 0.f;
            if (t == 0) tdone[0] = 0;
        }
        return;
    }

    const int e0 = blockIdx.x * EPW;
    const int cnt = min(EPW, E - e0);

    sval[t] = 0; sval[t + 256] = 0;
    __syncthreads();

    int er[16], ec[16];
#pragma unroll
    for (int i = 0; i < 16; ++i) {
        int le = i * 256 + t;
        if (le < cnt) {
            er[i] = row[e0 + le];
            ec[i] = col[e0 + le];
            atomicAdd(&sval[ec[i] >> BSH], 1);
            atomicAdd(&deg[ec[i]], 1);
        }
    }
    __syncthreads();
    horig[t] = sval[t]; horig[t + 256] = sval[t + 256];
    __syncthreads();
    for (int off = 1; off < 512; off <<= 1) {
        int a = (t >= off) ? sval[t - off] : 0;
        int b2 = sval[t + 256 - off];
        __syncthreads();
        sval[t] += a;
        sval[t + 256] += b2;
        __syncthreads();
    }
    for (int b = t; b < 512; b += 256) {
        int h = horig[b];
        pcnt[b] = sval[b] - h;
        gbase[b] = (h > 0 && b < NB) ? atomicAdd(&bfill[b], h) : 0;
    }
    __syncthreads();
#pragma unroll
    for (int i = 0; i < 16; ++i) {
        int le = i * 256 + t;
        if (le < cnt) {
            int b = ec[i] >> BSH;
            int j = atomicAdd(&pcnt[b], 1);
            staged[j] = (uintT)er[i] | ((uintT)ec[i] << 16);
            int lo = sval[b] - horig[b];
            target[j] = b * SEG + gbase[b] + (j - lo);
        }
    }
    __syncthreads();
    for (int s = t; s < cnt; s += 256) seg[target[s]] = staged[s];
}

// ---- per-bucket CSR scatter (padded x8, ushort records) + X->scaled fp8 ---
__global__ __launch_bounds__(256) void k_scatter(const int* __restrict__ bfill,
                                                 const uintT* __restrict__ seg,
                                                 const int* __restrict__ deg,
                                                 uintT* __restrict__ indptr,
                                                 ushortT* __restrict__ epack,
                                                 const float* __restrict__ X,
                                                 ucharT* __restrict__ Xb,
                                                 ucharT* __restrict__ Hb,
                                                 int N, int NB, int total4) {
    const int t = threadIdx.x;
    if ((int)blockIdx.x >= NB) {
        // X -> scaled fp8 conversion blocks (+ block 0: zero sentinel rows)
        int cb = (int)blockIdx.x - NB;
        if (cb == 0 && t < 16) {
            uint4 z = {0, 0, 0, 0};
            if (t < 8) reinterpret_cast<uint4*>(Xb + (size_t)N * CH)[t] = z;
            else       reinterpret_cast<uint4*>(Hb + (size_t)N * CH)[t - 8] = z;
        }
        int i = cb * 256 + t;
        if (i < total4) {
            float4 v = reinterpret_cast<const float4*>(X)[i];
            int rowi = i >> 5;   // 32 float4 per 128-ch row
            float iv = rsqrtf((float)deg[rowi] + 1.0f);
            int r0 = __builtin_amdgcn_cvt_pk_fp8_f32(v.x * iv, v.y * iv, 0, false);
            int r1 = __builtin_amdgcn_cvt_pk_fp8_f32(v.z * iv, v.w * iv, r0, true);
            reinterpret_cast<int*>(Xb)[i] = r1;
        }
        return;
    }

    __shared__ ushortT staged[SEGP];   // 10240 B
    __shared__ int hp[128];
    __shared__ int praw[128];
    __shared__ int pinc[128];
    __shared__ int pc[128];
    __shared__ int ptotS;
    const int b = blockIdx.x;
    const int cnt = bfill[b];
    const uintT* sp = seg + (size_t)b * SEG;

    if (t < 128) {
        int d = b * 128 + t;
        int dg = (d < N) ? deg[d] : 0;
        praw[t] = dg;
        hp[t] = (dg + 7) & ~7;
        pinc[t] = hp[t];
    }
    __syncthreads();
    for (int off = 1; off < 128; off <<= 1) {
        int a = (t >= off && t < 128) ? pinc[t - off] : 0;
        __syncthreads();
        if (t < 128) pinc[t] += a;
        __syncthreads();
    }
    if (t < 128) {
        int excl = pinc[t] - hp[t];
        pc[t] = excl;
        int d = b * 128 + t;
        if (d < N) indptr[d] = (uintT)(b * SEGP + excl) | ((uintT)(hp[t] >> 3) << 21);
        if (t == 127) ptotS = pinc[127];
    }
    __syncthreads();
    for (int s = t; s < cnt; s += 256) {
        uintT rc = sp[s];
        int j = atomicAdd(&pc[(rc >> 16) & 127], 1);
        staged[j] = (ushortT)(rc & 0xffffu);
    }
    __syncthreads();
    if (t < 128) {
        int base2 = pinc[t] - hp[t];
        for (int k = base2 + praw[t]; k < base2 + hp[t]; ++k) staged[k] = (ushortT)N;
    }
    __syncthreads();
    {
        int tot2 = ptotS >> 1;   // copy as uint pairs (ptot multiple of 8)
        uintT* dstw = reinterpret_cast<uintT*>(epack + (size_t)b * SEGP);
        const uintT* srcw = reinterpret_cast<const uintT*>(staged);
        for (int s = t; s < tot2; s += 256) dstw[s] = srcw[s];
    }
}

// ---- aggregation: 8 nodes/wave x 8 lanes x 16ch; ONE uint4 = 8 edge recs --
// acc = sum h'_src + h'_self, then *= invs(node). Pads hit zero row N (L1).
__global__ __launch_bounds__(256) void k_agg(const ucharT* __restrict__ H8,
                                             const ushortT* __restrict__ epack,
                                             const uintT* __restrict__ indptr,
                                             const int* __restrict__ deg,
                                             ucharT* __restrict__ Z8, int N) {
    const int wave = threadIdx.x >> 6, lane = threadIdx.x & 63;
    const int ng = lane >> 3;        // node slot 0..7
    const int l = lane & 7;          // 16 channels each (uint4)
    const int node = blockIdx.x * 32 + wave * 8 + ng;
    if (node >= N) return;

    const uint4* H4 = reinterpret_cast<const uint4*>(H8);
    const uint4* E4 = reinterpret_cast<const uint4*>(epack);

    int dgn = deg[node];                       // early load
    uintT v = indptr[node];
    int b8 = (int)(v & 0x1FFFFFu) >> 3;        // batch index
    int nb = (int)(v >> 21);                   // number of 8-edge batches

    float acc[16];
    {
        float d[16];
        dec16(H4[(size_t)node * 8 + l], d);    // self term h'_self
#pragma unroll
        for (int j = 0; j < 16; ++j) acc[j] = d[j];
    }

    auto proc = [&](uint4 e) {
        int s[8] = {(int)(e.x & 0xffffu), (int)(e.x >> 16),
                    (int)(e.y & 0xffffu), (int)(e.y >> 16),
                    (int)(e.z & 0xffffu), (int)(e.z >> 16),
                    (int)(e.w & 0xffffu), (int)(e.w >> 16)};
        uint4 g[8];
#pragma unroll
        for (int i = 0; i < 8; ++i) g[i] = H4[(size_t)s[i] * 8 + l];
#pragma unroll
        for (int i = 0; i < 8; ++i) {
            float d[16];
            dec16(g[i], d);
#pragma unroll
            for (int j = 0; j < 16; ++j) acc[j] += d[j];
        }
    };

    if (nb > 0) {
        uint4 e0 = E4[b8];
        for (int it = 1; it < nb; ++it) {
            uint4 e1 = E4[b8 + it];
            proc(e0);
            e0 = e1;
        }
        proc(e0);
    }

    float iv = rsqrtf((float)dgn + 1.0f);
#pragma unroll
    for (int j = 0; j < 16; ++j) acc[j] *= iv;

    uint4 o;
    {
        int r0 = __builtin_amdgcn_cvt_pk_fp8_f32(acc[0], acc[1], 0, false);
        r0 = __builtin_amdgcn_cvt_pk_fp8_f32(acc[2], acc[3], r0, true);
        int r1 = __builtin_amdgcn_cvt_pk_fp8_f32(acc[4], acc[5], 0, false);
        r1 = __builtin_amdgcn_cvt_pk_fp8_f32(acc[6], acc[7], r1, true);
        int r2 = __builtin_amdgcn_cvt_pk_fp8_f32(acc[8], acc[9], 0, false);
        r2 = __builtin_amdgcn_cvt_pk_fp8_f32(acc[10], acc[11], r2, true);
        int r3 = __builtin_amdgcn_cvt_pk_fp8_f32(acc[12], acc[13], 0, false);
        r3 = __builtin_amdgcn_cvt_pk_fp8_f32(acc[14], acc[15], r3, true);
        o.x = (uintT)r0; o.y = (uintT)r1; o.z = (uintT)r2; o.w = (uintT)r3;
    }
    reinterpret_cast<uint4*>(Z8)[(size_t)node * 8 + l] = o;
}

// ---- MFMA GEMM (GCN layers 1,2): fp8 in, SCALED fp8 out (h' = invs*relu) --
__global__ __launch_bounds__(256) void k_gemm(const ucharT* __restrict__ In8,
                                              const ushortT* __restrict__ Whi,
                                              const float* __restrict__ Bias,
                                              const int* __restrict__ deg,
                                              ucharT* __restrict__ Out8, int N) {
    __shared__ ushortT As[128 * SAF];   // 34816 B
    __shared__ ushortT Ws[128 * SAF];   // 34816 B
    __shared__ float invsL[128];

    const int tid = threadIdx.x;
    const int wave = tid >> 6, lane = tid & 63;
    const int quad = lane >> 4, l15 = lane & 15;
    const int mBase = (wave >> 1) * 64, nBase = (wave & 1) * 64;
    const int row0 = blockIdx.x * 128;
    const int r = tid >> 1, half = tid & 1;

    if (tid < 128) {
        int d = row0 + tid;
        invsL[tid] = (d < N) ? rsqrtf((float)deg[d] + 1.0f) : 0.f;
    }
    // stage A: full fp8 half-row (64B) -> bf16 LDS; stage W: bf16 copy
    {
        int grow = row0 + r;
        uint4 a8 = {0, 0, 0, 0}, b8 = {0, 0, 0, 0}, c8 = {0, 0, 0, 0}, d8v = {0, 0, 0, 0};
        if (grow < N) {
            const uint4* s = reinterpret_cast<const uint4*>(In8 + (size_t)grow * CH + half * 64);
            a8 = s[0]; b8 = s[1]; c8 = s[2]; d8v = s[3];
        }
        uintT wds[16] = {a8.x, a8.y, a8.z, a8.w, b8.x, b8.y, b8.z, b8.w,
                         c8.x, c8.y, c8.z, c8.w, d8v.x, d8v.y, d8v.z, d8v.w};
#pragma unroll
        for (int q = 0; q < 16; ++q) {
            float d[4];
            dec4(wds[q], d);
            uint2 o;
            o.x = (uintT)f2bf(d[0]) | ((uintT)f2bf(d[1]) << 16);
            o.y = (uintT)f2bf(d[2]) | ((uintT)f2bf(d[3]) << 16);
            *reinterpret_cast<uint2*>(&As[r * SAF + half * 64 + q * 4]) = o;
        }
        const uint4* sh = reinterpret_cast<const uint4*>(Whi + r * CH + half * 64);
#pragma unroll
        for (int q = 0; q < 8; ++q)
            *reinterpret_cast<uint4*>(&Ws[r * SAF + half * 64 + q * 8]) = sh[q];
    }
    __syncthreads();

    floatx4 acc[4][4];
    const floatx4 zero4 = {0.f, 0.f, 0.f, 0.f};
#pragma unroll
    for (int i = 0; i < 4; i++)
#pragma unroll
        for (int j = 0; j < 4; j++) acc[i][j] = zero4;

#pragma unroll
    for (int ks = 0; ks < 4; ++ks) {
        short8 af[4], wf[4];
#pragma unroll
        for (int mt = 0; mt < 4; ++mt)
            af[mt] = *reinterpret_cast<const short8*>(&As[(mBase + mt * 16 + l15) * SAF + ks * 32 + quad * 8]);
#pragma unroll
        for (int nt = 0; nt < 4; ++nt)
            wf[nt] = *reinterpret_cast<const short8*>(&Ws[(nBase + nt * 16 + l15) * SAF + ks * 32 + quad * 8]);
#pragma unroll
        for (int mt = 0; mt < 4; ++mt)
#pragma unroll
            for (int nt = 0; nt < 4; ++nt)
                acc[mt][nt] = __builtin_amdgcn_mfma_f32_16x16x32_bf16(af[mt], wf[nt], acc[mt][nt], 0, 0, 0);
    }
    __syncthreads();   // all LDS reads done; reuse As as epilogue buffer

    float bb[4];
#pragma unroll
    for (int nt = 0; nt < 4; ++nt) bb[nt] = Bias[nBase + nt * 16 + l15];

    ucharT* Cs8 = reinterpret_cast<ucharT*>(As);
#pragma unroll
    for (int mt = 0; mt < 4; ++mt)
#pragma unroll
        for (int nt = 0; nt < 4; ++nt)
#pragma unroll
            for (int r4 = 0; r4 < 4; ++r4) {
                int lrow = mBase + mt * 16 + quad * 4 + r4;
                float v = fmaxf(acc[mt][nt][r4] + bb[nt], 0.f) * invsL[lrow];
                int f8 = __builtin_amdgcn_cvt_pk_fp8_f32(v, 0.f, 0, false);
                Cs8[lrow * SC8 + nBase + nt * 16 + l15] = (ucharT)(f8 & 0xff);
            }
    __syncthreads();
    {
        int grow = row0 + r;
        if (grow < N) {
            const uint4* s4 = reinterpret_cast<const uint4*>(&Cs8[r * SC8 + half * 64]);
            uint4* dst = reinterpret_cast<uint4*>(Out8 + (size_t)grow * CH + half * 64);
#pragma unroll
            for (int q = 0; q < 4; ++q) dst[q] = s4[q];
        }
    }
}

// ---- fused tail: GEMM(W3) -> relu -> GEMM(FW1) -> FC2 -> pool -> softmax --
__global__ __launch_bounds__(256) void k_tail(const ucharT* __restrict__ Z8,
                                              const ushortT* __restrict__ W3hi,
                                              const float* __restrict__ B3,
                                              const ushortT* __restrict__ F1hi,
                                              const float* __restrict__ FB1,
                                              const float* __restrict__ FW2,
                                              const float* __restrict__ FB2,
                                              const int* __restrict__ batch,
                                              float* __restrict__ sums,
                                              float* __restrict__ cnts,
                                              float* __restrict__ out,
                                              int* __restrict__ tdone,
                                              int N, int G) {
    __shared__ ushortT Hf[128 * SAF];   // 34816 B: A-tile (Z), then H3 tile
    __shared__ ushortT Ws[128 * SAF];   // 34816 B: W3, then FW1
    __shared__ float rp0[256];
    __shared__ float rp1[256];
    __shared__ float ls[192];
    __shared__ int lastFlag;

    const int tid = threadIdx.x;
    const int wave = tid >> 6, lane = tid & 63;
    const int quad = lane >> 4, l15 = lane & 15;
    const int mBase = (wave >> 1) * 64, nBase = (wave & 1) * 64;
    const int row0 = blockIdx.x * 128;
    const int r = tid >> 1, half = tid & 1;

    // stage full Z tile: fp8 -> bf16 into Hf; stage Ws = W3 full
    {
        int grow = row0 + r;
        uint4 a8 = {0, 0, 0, 0}, b8 = {0, 0, 0, 0}, c8 = {0, 0, 0, 0}, d8v = {0, 0, 0, 0};
        if (grow < N) {
            const uint4* s = reinterpret_cast<const uint4*>(Z8 + (size_t)grow * CH + half * 64);
            a8 = s[0]; b8 = s[1]; c8 = s[2]; d8v = s[3];
        }
        uintT wds[16] = {a8.x, a8.y, a8.z, a8.w, b8.x, b8.y, b8.z, b8.w,
                         c8.x, c8.y, c8.z, c8.w, d8v.x, d8v.y, d8v.z, d8v.w};
#pragma unroll
        for (int q = 0; q < 16; ++q) {
            float d[4];
            dec4(wds[q], d);
            uint2 o;
            o.x = (uintT)f2bf(d[0]) | ((uintT)f2bf(d[1]) << 16);
            o.y = (uintT)f2bf(d[2]) | ((uintT)f2bf(d[3]) << 16);
            *reinterpret_cast<uint2*>(&Hf[r * SAF + half * 64 + q * 4]) = o;
        }
        const uint4* sh = reinterpret_cast<const uint4*>(W3hi + r * CH + half * 64);
#pragma unroll
        for (int q = 0; q < 8; ++q)
            *reinterpret_cast<uint4*>(&Ws[r * SAF + half * 64 + q * 8]) = sh[q];
    }
    __syncthreads();

    floatx4 acc[4][4];
    const floatx4 zero4 = {0.f, 0.f, 0.f, 0.f};
#pragma unroll
    for (int i = 0; i < 4; i++)
#pragma unroll
        for (int j = 0; j < 4; j++) acc[i][j] = zero4;

    // GEMM 1: Z @ W3
#pragma unroll
    for (int ks = 0; ks < 4; ++ks) {
        short8 af[4], wf[4];
#pragma unroll
        for (int mt = 0; mt < 4; ++mt)
            af[mt] = *reinterpret_cast<const short8*>(&Hf[(mBase + mt * 16 + l15) * SAF + ks * 32 + quad * 8]);
#pragma unroll
        for (int nt = 0; nt < 4; ++nt)
            wf[nt] = *reinterpret_cast<const short8*>(&Ws[(nBase + nt * 16 + l15) * SAF + ks * 32 + quad * 8]);
#pragma unroll
        for (int mt = 0; mt < 4; ++mt)
#pragma unroll
            for (int nt = 0; nt < 4; ++nt)
                acc[mt][nt] = __builtin_amdgcn_mfma_f32_16x16x32_bf16(af[mt], wf[nt], acc[mt][nt], 0, 0, 0);
    }
    __syncthreads();   // all GEMM1 LDS reads done

    // epilogue 1: H3 = relu(acc + b3) -> Hf ; restage Ws = FW1
    {
        float bb[4];
#pragma unroll
        for (int nt = 0; nt < 4; ++nt) bb[nt] = B3[nBase + nt * 16 + l15];
#pragma unroll
        for (int mt = 0; mt < 4; ++mt)
#pragma unroll
            for (int nt = 0; nt < 4; ++nt)
#pragma unroll
                for (int r4 = 0; r4 < 4; ++r4) {
                    int lrow = mBase + mt * 16 + quad * 4 + r4;
                    float v = fmaxf(acc[mt][nt][r4] + bb[nt], 0.f);
                    Hf[lrow * SAF + nBase + nt * 16 + l15] = f2bf(v);
                }
        const uint4* sh = reinterpret_cast<const uint4*>(F1hi + r * CH + half * 64);
#pragma unroll
        for (int q = 0; q < 8; ++q)
            *reinterpret_cast<uint4*>(&Ws[r * SAF + half * 64 + q * 8]) = sh[q];
    }
    __syncthreads();

    // GEMM 2: H3 @ FW1
#pragma unroll
    for (int i = 0; i < 4; i++)
#pragma unroll
        for (int j = 0; j < 4; j++) acc[i][j] = zero4;
#pragma unroll
    for (int ks = 0; ks < 4; ++ks) {
        short8 af[4], wf[4];
#pragma unroll
        for (int mt = 0; mt < 4; ++mt)
            af[mt] = *reinterpret_cast<const short8*>(&Hf[(mBase + mt * 16 + l15) * SAF + ks * 32 + quad * 8]);
#pragma unroll
        for (int nt = 0; nt < 4; ++nt)
            wf[nt] = *reinterpret_cast<const short8*>(&Ws[(nBase + nt * 16 + l15) * SAF + ks * 32 + quad * 8]);
#pragma unroll
        for (int mt = 0; mt < 4; ++mt)
#pragma unroll
            for (int nt = 0; nt < 4; ++nt)
                acc[mt][nt] = __builtin_amdgcn_mfma_f32_16x16x32_bf16(af[mt], wf[nt], acc[mt][nt], 0, 0, 0);
    }

    // FC2: per-row dot with fcW2 over this lane's 4 columns, reduce over l15
    {
        float bb[4];
#pragma unroll
        for (int nt = 0; nt < 4; ++nt) bb[nt] = FB1[nBase + nt * 16 + l15];
        float w20[4], w21[4];
#pragma unroll
        for (int nt = 0; nt < 4; ++nt) {
            float2 wv = *reinterpret_cast<const float2*>(FW2 + 2 * (nBase + nt * 16 + l15));
            w20[nt] = wv.x;
            w21[nt] = wv.y;
        }
#pragma unroll
        for (int mt = 0; mt < 4; ++mt)
#pragma unroll
            for (int r4 = 0; r4 < 4; ++r4) {
                float d0 = 0.f, d1 = 0.f;
#pragma unroll
                for (int nt = 0; nt < 4; ++nt) {
                    float v = fmaxf(acc[mt][nt][r4] + bb[nt], 0.f);
                    d0 += v * w20[nt];
                    d1 += v * w21[nt];
                }
#pragma unroll
                for (int m = 8; m >= 1; m >>= 1) {
                    d0 += __shfl_xor(d0, m, 64);
                    d1 += __shfl_xor(d1, m, 64);
                }
                if (l15 == 0) {
                    int lrow = mBase + mt * 16 + quad * 4 + r4;
                    rp0[lrow * 2 + (wave & 1)] = d0;
                    rp1[lrow * 2 + (wave & 1)] = d1;
                }
            }
    }
    if (tid < 192) ls[tid] = 0.f;
    __syncthreads();

    if (tid < 128) {
        int node = row0 + tid;
        if (node < N) {
            float d0 = rp0[tid * 2] + rp0[tid * 2 + 1] + FB2[0];
            float d1 = rp1[tid * 2] + rp1[tid * 2 + 1] + FB2[1];
            int g = batch[node];
            atomicAdd(&ls[g], d0);
            atomicAdd(&ls[64 + g], d1);
            atomicAdd(&ls[128 + g], 1.0f);
        }
    }
    __syncthreads();
    if (tid < 64) {
        float c = ls[128 + tid];
        if (c != 0.f) {
            atomicAdd(&sums[2 * tid], ls[tid]);
            atomicAdd(&sums[2 * tid + 1], ls[64 + tid]);
            atomicAdd(&cnts[tid], c);
        }
    }
    __syncthreads();   // drains this block's global atomics

    // completion counter; last block computes softmax (coherent-point reads)
    if (tid == 0) {
        int old = atomicAdd(tdone, 1);
        lastFlag = (old == (int)gridDim.x - 1) ? 1 : 0;
    }
    __syncthreads();
    if (lastFlag && tid < G) {
        int g = tid;
        float c = fmaxf(atomicAdd(&cnts[g], 0.f), 1.0f);
        float p0 = atomicAdd(&sums[2 * g], 0.f) / c;
        float p1 = atomicAdd(&sums[2 * g + 1], 0.f) / c;
        float m = fmaxf(p0, p1);
        float e0 = expf(p0 - m), e1 = expf(p1 - m);
        float inv = 1.f / (e0 + e1);
        out[2 * g] = e0 * inv;
        out[2 * g + 1] = e1 * inv;
    }
}

// ---------------------------------------------------------------------------
extern "C" void kernel_launch(void* const* d_in, const int* in_sizes, int n_in,
                              void* d_out, int out_size, void* d_ws, size_t ws_size,
                              hipStream_t stream) {
    const float* X   = (const float*)d_in[0];
    const int* EI    = (const int*)d_in[1];
    const int* BATCH = (const int*)d_in[2];
    const float* W1  = (const float*)d_in[3];
    const float* B1  = (const float*)d_in[4];
    const float* W2  = (const float*)d_in[5];
    const float* B2  = (const float*)d_in[6];
    const float* W3  = (const float*)d_in[7];
    const float* B3  = (const float*)d_in[8];
    const float* FW1 = (const float*)d_in[9];
    const float* FB1 = (const float*)d_in[10];
    const float* FW2 = (const float*)d_in[11];
    const float* FB2 = (const float*)d_in[12];

    const int N = in_sizes[0] / CH;
    const int E = in_sizes[1] / 2;
    const int G = out_size / 2;
    const int* rowp = EI;
    const int* colp = EI + E;
    const int NB = (N + 127) >> BSH;

    char* w = (char*)d_ws;
    auto alloc = [&](size_t bytes) -> char* {
        char* p = w;
        w += (bytes + 255) & ~(size_t)255;
        return p;
    };
    ucharT*  Z8    = (ucharT*)alloc((size_t)N * CH);          // fp8 Z (agg out)
    ucharT*  Hb8   = (ucharT*)alloc((size_t)(N + 1) * CH);    // fp8 h' (sentinel row N)
    ucharT*  Xb8   = (ucharT*)alloc((size_t)(N + 1) * CH);    // fp8 scaled X (sentinel row N)
    ushortT* WhiA  = (ushortT*)alloc((size_t)4 * 16384 * 2);
    int*   bfill   = (int*)alloc((size_t)NB * 4);             // adjacent to deg:
    int*   deg     = (int*)alloc((size_t)N * 4);              //   one memset covers both
    uintT* indptr  = (uintT*)alloc((size_t)N * 4);
    ushortT* epack = (ushortT*)alloc((size_t)NB * SEGP * 2);
    uintT* seg     = (uintT*)alloc((size_t)NB * SEG * 4);
    float* sums    = (float*)alloc((size_t)G * 3 * 4);        // sums | cnts
    float* cnts    = sums + 2 * G;
    int*   tdone   = (int*)alloc(256);

    const int nbAgg  = (N + 31) / 32;
    const int nbGemm = (N + 127) / 128;
    const int nbBin  = (E + EPW - 1) / EPW;
    const int total4 = N * CH / 4;
    const int nbXc   = (total4 + 255) / 256;

    const size_t zeroBytes = (((size_t)NB * 4 + 255) & ~(size_t)255) + (size_t)N * 4;
    hipMemsetAsync(bfill, 0, zeroBytes, stream);   // bfill + deg
    k_bin<<<nbBin + 256, 256, 0, stream>>>(rowp, colp, bfill, deg, seg,
                                           W1, W2, W3, FW1, WhiA, sums, tdone,
                                           E, nbBin, NB, G);
    k_scatter<<<NB + nbXc, 256, 0, stream>>>(bfill, seg, deg, indptr, epack,
                                             X, Xb8, Hb8, N, NB, total4);

    // layer 1
    k_agg<<<nbAgg, 256, 0, stream>>>(Xb8, epack, indptr, deg, Z8, N);
    k_gemm<<<nbGemm, 256, 0, stream>>>(Z8, WhiA, B1, deg, Hb8, N);
    // layer 2
    k_agg<<<nbAgg, 256, 0, stream>>>(Hb8, epack, indptr, deg, Z8, N);
    k_gemm<<<nbGemm, 256, 0, stream>>>(Z8, WhiA + 16384, B2, deg, Hb8, N);
    // layer 3 agg, then fused tail (GEMM W3 + FC1 + FC2 + pool + softmax)
    k_agg<<<nbAgg, 256, 0, stream>>>(Hb8, epack, indptr, deg, Z8, N);
    k_tail<<<nbGemm, 256, 0, stream>>>(Z8, WhiA + 2 * 16384, B3,
                                       WhiA + 3 * 16384, FB1, FW2, FB2,
                                       BATCH, sums, cnts, (float*)d_out, tdone, N, G);
}

// Round 3
// 203.868 us; speedup vs baseline: 1.0854x; 1.0854x over previous
//
#include <hip/hip_runtime.h>

// ---------------------------------------------------------------------------
// colorableGNN: 3x GCN(128->128) + FC(128->128) + FC(128->2) + mean-pool + softmax
// R17 (delta vs R15 -- R16 scaled-H REVERTED, it regressed 204->221):
//  - R15 structure restored: weighted 4B edge records (src|bf16nrm), X-conv
//    unscaled fp8 overlapped in k_bin, k_binvs computes invs, k_gemm/k_tail
//    full-K single-stage LDS, fused softmax via tdone counter.
//  - Lever 1: k_bin EPW 4096->2048 (196->391 binning blocks; >=1 per CU,
//    halves the per-block two-phase-scan long pole).
//  - Lever 2: k_scatter pads each node's list to x8 with ZERO-WEIGHT records
//    (src=0, nrm=0 -> contributes exactly 0.0f, bitwise-identical accum) in
//    FIXED per-bucket segments (SEGP); indptr packs base|nbatches. k_agg
//    loads 8 edges as 2x uint4 (was 8 scalar loads), no remainder branch,
//    no indptr[node+1]. Bucket-scan/bbase machinery deleted.
// NOTE: gather kernels need occupancy; never fuse agg into GEMM (R7: 104us).
// ---------------------------------------------------------------------------

#define CH 128
#define BSH 7              // 128 dst nodes per bucket
#define SEG 4096           // raw segment capacity (records) per bucket
#define SEGP 5120          // padded epack segment (4B records) per bucket
#define EPW 2048           // edges per phase-1 workgroup (R17: was 4096)
#define SAF 136            // LDS stride full-K tiles (shorts; 272B = 17*16B)
#define SC8 144            // fp8 epilogue stride (bytes)

typedef unsigned short ushortT;
typedef unsigned int uintT;
typedef unsigned char ucharT;
typedef __attribute__((ext_vector_type(8))) short short8;
typedef __attribute__((ext_vector_type(4))) float floatx4;
typedef __attribute__((ext_vector_type(2))) float floatx2;

__device__ __forceinline__ float bf2f(uintT u) {
    return __uint_as_float(u << 16);
}
__device__ __forceinline__ ushortT f2bf(float f) {
    uintT x = __float_as_uint(f);
    return (ushortT)((x + 0x7fffu + ((x >> 16) & 1u)) >> 16);
}
__device__ __forceinline__ void dec4(uintT u, float* o) {
    floatx2 lo = __builtin_amdgcn_cvt_pk_f32_fp8((int)u, false);
    floatx2 hi = __builtin_amdgcn_cvt_pk_f32_fp8((int)u, true);
    o[0] = lo.x; o[1] = lo.y; o[2] = hi.x; o[3] = hi.y;
}
__device__ __forceinline__ void dec16(uint4 v, float* o) {
    dec4(v.x, o); dec4(v.y, o + 4); dec4(v.z, o + 8); dec4(v.w, o + 12);
}

// ---- phase 1: bin edges into dst-buckets; records packed src|(dst<<16) ----
// extra blocks: [NBB, NBB+256) weight prep (+block0 zeroes sums/tdone);
//               [NBB+256, ...) X -> fp8 (unscaled, overlapped)
__global__ __launch_bounds__(256) void k_bin(const int* __restrict__ row,
                                             const int* __restrict__ col,
                                             int* __restrict__ bfill,
                                             uintT* __restrict__ seg,
                                             const float* __restrict__ X,
                                             ucharT* __restrict__ Xb,
                                             const float* __restrict__ w0,
                                             const float* __restrict__ w1,
                                             const float* __restrict__ w2,
                                             const float* __restrict__ w3,
                                             ushortT* __restrict__ Whi,
                                             float* __restrict__ sums,
                                             int* __restrict__ tdone,
                                             int E, int NBB, int NB, int G,
                                             int total4) {
    __shared__ uintT staged[EPW];   // 8 KB
    __shared__ int target[EPW];     // 8 KB
    __shared__ int sval[512];
    __shared__ int horig[512];
    __shared__ int pcnt[512];
    __shared__ int gbase[512];
    const int t = threadIdx.x;

    if ((int)blockIdx.x >= NBB) {
        int bb = (int)blockIdx.x - NBB;
        if (bb < 256) {
            // weight prep: transpose + bf16
            int idx = bb * 256 + t;   // 0..65535
            int m = idx >> 14;
            int r2 = idx & 16383;
            int n = r2 >> 7;
            int k = r2 & 127;
            const float* W = (m == 0) ? w0 : (m == 1) ? w1 : (m == 2) ? w2 : w3;
            Whi[m * 16384 + n * CH + k] = f2bf(W[k * CH + n]);
            if (bb == 0) {
                if (t < 3 * G) sums[t] = 0.f;
                if (t == 0) tdone[0] = 0;
            }
        } else {
            // X -> fp8 (unscaled)
            int i = (bb - 256) * 256 + t;
            if (i < total4) {
                float4 v = reinterpret_cast<const float4*>(X)[i];
                int r0 = __builtin_amdgcn_cvt_pk_fp8_f32(v.x, v.y, 0, false);
                int r1 = __builtin_amdgcn_cvt_pk_fp8_f32(v.z, v.w, r0, true);
                reinterpret_cast<int*>(Xb)[i] = r1;
            }
        }
        return;
    }

    const int e0 = blockIdx.x * EPW;
    const int cnt = min(EPW, E - e0);

    sval[t] = 0; sval[t + 256] = 0;
    __syncthreads();

    int er[8], ec[8];
#pragma unroll
    for (int i = 0; i < 8; ++i) {
        int le = i * 256 + t;
        if (le < cnt) {
            er[i] = row[e0 + le];
            ec[i] = col[e0 + le];
            atomicAdd(&sval[ec[i] >> BSH], 1);
        }
    }
    __syncthreads();
    horig[t] = sval[t]; horig[t + 256] = sval[t + 256];
    __syncthreads();
    for (int off = 1; off < 512; off <<= 1) {
        int a = (t >= off) ? sval[t - off] : 0;
        int b2 = sval[t + 256 - off];
        __syncthreads();
        sval[t] += a;
        sval[t + 256] += b2;
        __syncthreads();
    }
    for (int b = t; b < 512; b += 256) {
        int h = horig[b];
        pcnt[b] = sval[b] - h;
        gbase[b] = (h > 0 && b < NB) ? atomicAdd(&bfill[b], h) : 0;
    }
    __syncthreads();
#pragma unroll
    for (int i = 0; i < 8; ++i) {
        int le = i * 256 + t;
        if (le < cnt) {
            int b = ec[i] >> BSH;
            int j = atomicAdd(&pcnt[b], 1);
            staged[j] = (uintT)er[i] | ((uintT)ec[i] << 16);
            int lo = sval[b] - horig[b];
            target[j] = b * SEG + gbase[b] + (j - lo);
        }
    }
    __syncthreads();
    for (int s = t; s < cnt; s += 256) seg[target[s]] = staged[s];
}

// ---- per-bucket degree -> invs (grid = NB) --------------------------------
__global__ __launch_bounds__(512) void k_binvs(const int* __restrict__ bfill,
                                               const uintT* __restrict__ seg,
                                               float* __restrict__ invs,
                                               int NB, int N) {
    const int b = blockIdx.x;
    const int t = threadIdx.x;
    __shared__ int h[128];
    if (t < 128) h[t] = 0;
    __syncthreads();
    int cnt = bfill[b];
    const uintT* sp = seg + (size_t)b * SEG;
    for (int s = t; s < cnt; s += 512) atomicAdd(&h[(sp[s] >> 16) & 127], 1);
    __syncthreads();
    int d = b * 128 + t;
    if (t < 128 && d < N) invs[d] = rsqrtf((float)h[t] + 1.0f);
}

// ---- per-bucket CSR scatter: padded x8 4B records, fixed segments ---------
__global__ __launch_bounds__(256) void k_scatter(const int* __restrict__ bfill,
                                                 const uintT* __restrict__ seg,
                                                 const float* __restrict__ invs,
                                                 uintT* __restrict__ indptr,
                                                 uintT* __restrict__ epack,
                                                 int N, int NB) {
    __shared__ __align__(16) uintT staged[SEGP];   // 20 KB
    __shared__ int h[128];
    __shared__ int pinc[128];
    __shared__ int pc[128];
    __shared__ float invL[128];
    __shared__ int ptotS;
    const int t = threadIdx.x;
    const int b = blockIdx.x;
    const int cnt = bfill[b];
    const uintT* sp = seg + (size_t)b * SEG;

    if (t < 128) {
        h[t] = 0;
        int d = b * 128 + t;
        invL[t] = (d < N) ? invs[d] : 0.f;
    }
    __syncthreads();
    for (int s = t; s < cnt; s += 256) atomicAdd(&h[(sp[s] >> 16) & 127], 1);
    __syncthreads();
    int praw = 0, hp = 0;
    if (t < 128) {
        praw = h[t];
        hp = (praw + 7) & ~7;
        pinc[t] = hp;
    }
    __syncthreads();
    for (int off = 1; off < 128; off <<= 1) {
        int a = (t >= off && t < 128) ? pinc[t - off] : 0;
        __syncthreads();
        if (t < 128) pinc[t] += a;
        __syncthreads();
    }
    int excl = 0;
    if (t < 128) {
        excl = pinc[t] - hp;
        pc[t] = excl;
        int d = b * 128 + t;
        if (d < N) indptr[d] = (uintT)(b * SEGP + excl) | ((uintT)(hp >> 3) << 21);
        if (t == 127) ptotS = pinc[127];
    }
    __syncthreads();
    for (int s = t; s < cnt; s += 256) {
        uintT rc = sp[s];
        int src = (int)(rc & 0xffffu);
        int d7 = (int)(rc >> 16) & 127;
        int j = atomicAdd(&pc[d7], 1);
        float nrm = invs[src] * invL[d7];
        staged[j] = (uintT)src | ((uintT)f2bf(nrm) << 16);
    }
    __syncthreads();
    if (t < 128) {
        for (int k = excl + praw; k < excl + hp; ++k) staged[k] = 0u;  // zero-weight pad
    }
    __syncthreads();
    {
        int tot4 = ptotS >> 2;   // ptot is a multiple of 8
        uint4* dstw = reinterpret_cast<uint4*>(epack + (size_t)b * SEGP);
        const uint4* srcw = reinterpret_cast<const uint4*>(staged);
        for (int s = t; s < tot4; s += 256) dstw[s] = srcw[s];
    }
}

// ---- aggregation: 8 nodes/wave x 8 lanes x 16ch; 2x uint4 = 8 edge recs ---
// weighted records (src|bf16nrm); pads are (0,0) -> contribute exactly 0.
__global__ __launch_bounds__(256) void k_agg(const ucharT* __restrict__ H8,
                                             const uintT* __restrict__ epack,
                                             const uintT* __restrict__ indptr,
                                             const float* __restrict__ invs,
                                             ucharT* __restrict__ Z8, int N) {
    const int wave = threadIdx.x >> 6, lane = threadIdx.x & 63;
    const int ng = lane >> 3;        // node slot 0..7
    const int l = lane & 7;          // 16 channels each (uint4)
    const int node = blockIdx.x * 32 + wave * 8 + ng;
    if (node >= N) return;

    const uint4* H4 = reinterpret_cast<const uint4*>(H8);
    const uint4* E4 = reinterpret_cast<const uint4*>(epack);

    uintT v = indptr[node];
    int q0 = (int)(v & 0x1FFFFFu) >> 2;   // uint4 index (4 recs each), even
    int nb = (int)(v >> 21);              // number of 8-edge batches

    float acc[16];
    {
        float sn = invs[node];
        float sn2 = sn * sn;
        float d[16];
        dec16(H4[(size_t)node * 8 + l], d);
#pragma unroll
        for (int j = 0; j < 16; ++j) acc[j] = sn2 * d[j];
    }

    auto proc = [&](uint4 ea, uint4 eb) {
        uintT rec[8] = {ea.x, ea.y, ea.z, ea.w, eb.x, eb.y, eb.z, eb.w};
        uint4 g[8];
#pragma unroll
        for (int i = 0; i < 8; ++i)
            g[i] = H4[(size_t)(int)(rec[i] & 0xffffu) * 8 + l];
#pragma unroll
        for (int i = 0; i < 8; ++i) {
            float wv = bf2f(rec[i] >> 16);
            float d[16];
            dec16(g[i], d);
#pragma unroll
            for (int j = 0; j < 16; ++j) acc[j] += wv * d[j];
        }
    };

    if (nb > 0) {
        uint4 ea = E4[q0], eb = E4[q0 + 1];
        for (int it = 1; it < nb; ++it) {
            uint4 na = E4[q0 + 2 * it], nbv = E4[q0 + 2 * it + 1];
            proc(ea, eb);
            ea = na; eb = nbv;
        }
        proc(ea, eb);
    }

    uint4 o;
    {
        int r0 = __builtin_amdgcn_cvt_pk_fp8_f32(acc[0], acc[1], 0, false);
        r0 = __builtin_amdgcn_cvt_pk_fp8_f32(acc[2], acc[3], r0, true);
        int r1 = __builtin_amdgcn_cvt_pk_fp8_f32(acc[4], acc[5], 0, false);
        r1 = __builtin_amdgcn_cvt_pk_fp8_f32(acc[6], acc[7], r1, true);
        int r2 = __builtin_amdgcn_cvt_pk_fp8_f32(acc[8], acc[9], 0, false);
        r2 = __builtin_amdgcn_cvt_pk_fp8_f32(acc[10], acc[11], r2, true);
        int r3 = __builtin_amdgcn_cvt_pk_fp8_f32(acc[12], acc[13], 0, false);
        r3 = __builtin_amdgcn_cvt_pk_fp8_f32(acc[14], acc[15], r3, true);
        o.x = (uintT)r0; o.y = (uintT)r1; o.z = (uintT)r2; o.w = (uintT)r3;
    }
    reinterpret_cast<uint4*>(Z8)[(size_t)node * 8 + l] = o;
}

// ---- MFMA GEMM (GCN layers 1,2): fp8 in, fp8 out, full-K single stage -----
__global__ __launch_bounds__(256) void k_gemm(const ucharT* __restrict__ In8,
                                              const ushortT* __restrict__ Whi,
                                              const float* __restrict__ Bias,
                                              ucharT* __restrict__ Out8, int N) {
    __shared__ ushortT As[128 * SAF];   // 34816 B
    __shared__ ushortT Ws[128 * SAF];   // 34816 B

    const int tid = threadIdx.x;
    const int wave = tid >> 6, lane = tid & 63;
    const int quad = lane >> 4, l15 = lane & 15;
    const int mBase = (wave >> 1) * 64, nBase = (wave & 1) * 64;
    const int row0 = blockIdx.x * 128;
    const int r = tid >> 1, half = tid & 1;

    // stage A: full fp8 half-row (64B) -> bf16 LDS; stage W: bf16 copy
    {
        int grow = row0 + r;
        uint4 a8 = {0, 0, 0, 0}, b8 = {0, 0, 0, 0}, c8 = {0, 0, 0, 0}, d8v = {0, 0, 0, 0};
        if (grow < N) {
            const uint4* s = reinterpret_cast<const uint4*>(In8 + (size_t)grow * CH + half * 64);
            a8 = s[0]; b8 = s[1]; c8 = s[2]; d8v = s[3];
        }
        uintT wds[16] = {a8.x, a8.y, a8.z, a8.w, b8.x, b8.y, b8.z, b8.w,
                         c8.x, c8.y, c8.z, c8.w, d8v.x, d8v.y, d8v.z, d8v.w};
#pragma unroll
        for (int q = 0; q < 16; ++q) {
            float d[4];
            dec4(wds[q], d);
            uint2 o;
            o.x = (uintT)f2bf(d[0]) | ((uintT)f2bf(d[1]) << 16);
            o.y = (uintT)f2bf(d[2]) | ((uintT)f2bf(d[3]) << 16);
            *reinterpret_cast<uint2*>(&As[r * SAF + half * 64 + q * 4]) = o;
        }
        const uint4* sh = reinterpret_cast<const uint4*>(Whi + r * CH + half * 64);
#pragma unroll
        for (int q = 0; q < 8; ++q)
            *reinterpret_cast<uint4*>(&Ws[r * SAF + half * 64 + q * 8]) = sh[q];
    }
    __syncthreads();

    floatx4 acc[4][4];
    const floatx4 zero4 = {0.f, 0.f, 0.f, 0.f};
#pragma unroll
    for (int i = 0; i < 4; i++)
#pragma unroll
        for (int j = 0; j < 4; j++) acc[i][j] = zero4;

#pragma unroll
    for (int ks = 0; ks < 4; ++ks) {
        short8 af[4], wf[4];
#pragma unroll
        for (int mt = 0; mt < 4; ++mt)
            af[mt] = *reinterpret_cast<const short8*>(&As[(mBase + mt * 16 + l15) * SAF + ks * 32 + quad * 8]);
#pragma unroll
        for (int nt = 0; nt < 4; ++nt)
            wf[nt] = *reinterpret_cast<const short8*>(&Ws[(nBase + nt * 16 + l15) * SAF + ks * 32 + quad * 8]);
#pragma unroll
        for (int mt = 0; mt < 4; ++mt)
#pragma unroll
            for (int nt = 0; nt < 4; ++nt)
                acc[mt][nt] = __builtin_amdgcn_mfma_f32_16x16x32_bf16(af[mt], wf[nt], acc[mt][nt], 0, 0, 0);
    }
    __syncthreads();   // all LDS reads done; reuse As as epilogue buffer

    float bb[4];
#pragma unroll
    for (int nt = 0; nt < 4; ++nt) bb[nt] = Bias[nBase + nt * 16 + l15];

    ucharT* Cs8 = reinterpret_cast<ucharT*>(As);
#pragma unroll
    for (int mt = 0; mt < 4; ++mt)
#pragma unroll
        for (int nt = 0; nt < 4; ++nt)
#pragma unroll
            for (int r4 = 0; r4 < 4; ++r4) {
                int lrow = mBase + mt * 16 + quad * 4 + r4;
                float v = fmaxf(acc[mt][nt][r4] + bb[nt], 0.f);
                int f8 = __builtin_amdgcn_cvt_pk_fp8_f32(v, 0.f, 0, false);
                Cs8[lrow * SC8 + nBase + nt * 16 + l15] = (ucharT)(f8 & 0xff);
            }
    __syncthreads();
    {
        int grow = row0 + r;
        if (grow < N) {
            const uint4* s4 = reinterpret_cast<const uint4*>(&Cs8[r * SC8 + half * 64]);
            uint4* dst = reinterpret_cast<uint4*>(Out8 + (size_t)grow * CH + half * 64);
#pragma unroll
            for (int q = 0; q < 4; ++q) dst[q] = s4[q];
        }
    }
}

// ---- fused tail: GEMM(W3) -> relu -> GEMM(FW1) -> FC2 -> pool -> softmax --
__global__ __launch_bounds__(256) void k_tail(const ucharT* __restrict__ Z8,
                                              const ushortT* __restrict__ W3hi,
                                              const float* __restrict__ B3,
                                              const ushortT* __restrict__ F1hi,
                                              const float* __restrict__ FB1,
                                              const float* __restrict__ FW2,
                                              const float* __restrict__ FB2,
                                              const int* __restrict__ batch,
                                              float* __restrict__ sums,
                                              float* __restrict__ cnts,
                                              float* __restrict__ out,
                                              int* __restrict__ tdone,
                                              int N, int G) {
    __shared__ ushortT Hf[128 * SAF];   // 34816 B: A-tile (Z), then H3 tile
    __shared__ ushortT Ws[128 * SAF];   // 34816 B: W3, then FW1
    __shared__ float rp0[256];
    __shared__ float rp1[256];
    __shared__ float ls[192];
    __shared__ int lastFlag;

    const int tid = threadIdx.x;
    const int wave = tid >> 6, lane = tid & 63;
    const int quad = lane >> 4, l15 = lane & 15;
    const int mBase = (wave >> 1) * 64, nBase = (wave & 1) * 64;
    const int row0 = blockIdx.x * 128;
    const int r = tid >> 1, half = tid & 1;

    // stage full Z tile: fp8 -> bf16 into Hf; stage Ws = W3 full
    {
        int grow = row0 + r;
        uint4 a8 = {0, 0, 0, 0}, b8 = {0, 0, 0, 0}, c8 = {0, 0, 0, 0}, d8v = {0, 0, 0, 0};
        if (grow < N) {
            const uint4* s = reinterpret_cast<const uint4*>(Z8 + (size_t)grow * CH + half * 64);
            a8 = s[0]; b8 = s[1]; c8 = s[2]; d8v = s[3];
        }
        uintT wds[16] = {a8.x, a8.y, a8.z, a8.w, b8.x, b8.y, b8.z, b8.w,
                         c8.x, c8.y, c8.z, c8.w, d8v.x, d8v.y, d8v.z, d8v.w};
#pragma unroll
        for (int q = 0; q < 16; ++q) {
            float d[4];
            dec4(wds[q], d);
            uint2 o;
            o.x = (uintT)f2bf(d[0]) | ((uintT)f2bf(d[1]) << 16);
            o.y = (uintT)f2bf(d[2]) | ((uintT)f2bf(d[3]) << 16);
            *reinterpret_cast<uint2*>(&Hf[r * SAF + half * 64 + q * 4]) = o;
        }
        const uint4* sh = reinterpret_cast<const uint4*>(W3hi + r * CH + half * 64);
#pragma unroll
        for (int q = 0; q < 8; ++q)
            *reinterpret_cast<uint4*>(&Ws[r * SAF + half * 64 + q * 8]) = sh[q];
    }
    __syncthreads();

    floatx4 acc[4][4];
    const floatx4 zero4 = {0.f, 0.f, 0.f, 0.f};
#pragma unroll
    for (int i = 0; i < 4; i++)
#pragma unroll
        for (int j = 0; j < 4; j++) acc[i][j] = zero4;

    // GEMM 1: Z @ W3
#pragma unroll
    for (int ks = 0; ks < 4; ++ks) {
        short8 af[4], wf[4];
#pragma unroll
        for (int mt = 0; mt < 4; ++mt)
            af[mt] = *reinterpret_cast<const short8*>(&Hf[(mBase + mt * 16 + l15) * SAF + ks * 32 + quad * 8]);
#pragma unroll
        for (int nt = 0; nt < 4; ++nt)
            wf[nt] = *reinterpret_cast<const short8*>(&Ws[(nBase + nt * 16 + l15) * SAF + ks * 32 + quad * 8]);
#pragma unroll
        for (int mt = 0; mt < 4; ++mt)
#pragma unroll
            for (int nt = 0; nt < 4; ++nt)
                acc[mt][nt] = __builtin_amdgcn_mfma_f32_16x16x32_bf16(af[mt], wf[nt], acc[mt][nt], 0, 0, 0);
    }
    __syncthreads();   // all GEMM1 LDS reads done

    // epilogue 1: H3 = relu(acc + b3) -> Hf ; restage Ws = FW1
    {
        float bb[4];
#pragma unroll
        for (int nt = 0; nt < 4; ++nt) bb[nt] = B3[nBase + nt * 16 + l15];
#pragma unroll
        for (int mt = 0; mt < 4; ++mt)
#pragma unroll
            for (int nt = 0; nt < 4; ++nt)
#pragma unroll
                for (int r4 = 0; r4 < 4; ++r4) {
                    int lrow = mBase + mt * 16 + quad * 4 + r4;
                    float v = fmaxf(acc[mt][nt][r4] + bb[nt], 0.f);
                    Hf[lrow * SAF + nBase + nt * 16 + l15] = f2bf(v);
                }
        const uint4* sh = reinterpret_cast<const uint4*>(F1hi + r * CH + half * 64);
#pragma unroll
        for (int q = 0; q < 8; ++q)
            *reinterpret_cast<uint4*>(&Ws[r * SAF + half * 64 + q * 8]) = sh[q];
    }
    __syncthreads();

    // GEMM 2: H3 @ FW1
#pragma unroll
    for (int i = 0; i < 4; i++)
#pragma unroll
        for (int j = 0; j < 4; j++) acc[i][j] = zero4;
#pragma unroll
    for (int ks = 0; ks < 4; ++ks) {
        short8 af[4], wf[4];
#pragma unroll
        for (int mt = 0; mt < 4; ++mt)
            af[mt] = *reinterpret_cast<const short8*>(&Hf[(mBase + mt * 16 + l15) * SAF + ks * 32 + quad * 8]);
#pragma unroll
        for (int nt = 0; nt < 4; ++nt)
            wf[nt] = *reinterpret_cast<const short8*>(&Ws[(nBase + nt * 16 + l15) * SAF + ks * 32 + quad * 8]);
#pragma unroll
        for (int mt = 0; mt < 4; ++mt)
#pragma unroll
            for (int nt = 0; nt < 4; ++nt)
                acc[mt][nt] = __builtin_amdgcn_mfma_f32_16x16x32_bf16(af[mt], wf[nt], acc[mt][nt], 0, 0, 0);
    }

    // FC2: per-row dot with fcW2 over this lane's 4 columns, reduce over l15
    {
        float bb[4];
#pragma unroll
        for (int nt = 0; nt < 4; ++nt) bb[nt] = FB1[nBase + nt * 16 + l15];
        float w20[4], w21[4];
#pragma unroll
        for (int nt = 0; nt < 4; ++nt) {
            float2 wv = *reinterpret_cast<const float2*>(FW2 + 2 * (nBase + nt * 16 + l15));
            w20[nt] = wv.x;
            w21[nt] = wv.y;
        }
#pragma unroll
        for (int mt = 0; mt < 4; ++mt)
#pragma unroll
            for (int r4 = 0; r4 < 4; ++r4) {
                float d0 = 0.f, d1 = 0.f;
#pragma unroll
                for (int nt = 0; nt < 4; ++nt) {
                    float v = fmaxf(acc[mt][nt][r4] + bb[nt], 0.f);
                    d0 += v * w20[nt];
                    d1 += v * w21[nt];
                }
#pragma unroll
                for (int m = 8; m >= 1; m >>= 1) {
                    d0 += __shfl_xor(d0, m, 64);
                    d1 += __shfl_xor(d1, m, 64);
                }
                if (l15 == 0) {
                    int lrow = mBase + mt * 16 + quad * 4 + r4;
                    rp0[lrow * 2 + (wave & 1)] = d0;
                    rp1[lrow * 2 + (wave & 1)] = d1;
                }
            }
    }
    if (tid < 192) ls[tid] = 0.f;
    __syncthreads();

    if (tid < 128) {
        int node = row0 + tid;
        if (node < N) {
            float d0 = rp0[tid * 2] + rp0[tid * 2 + 1] + FB2[0];
            float d1 = rp1[tid * 2] + rp1[tid * 2 + 1] + FB2[1];
            int g = batch[node];
            atomicAdd(&ls[g], d0);
            atomicAdd(&ls[64 + g], d1);
            atomicAdd(&ls[128 + g], 1.0f);
        }
    }
    __syncthreads();
    if (tid < 64) {
        float c = ls[128 + tid];
        if (c != 0.f) {
            atomicAdd(&sums[2 * tid], ls[tid]);
            atomicAdd(&sums[2 * tid + 1], ls[64 + tid]);
            atomicAdd(&cnts[tid], c);
        }
    }
    __syncthreads();   // drains this block's global atomics

    // completion counter; last block computes softmax (coherent-point reads)
    if (tid == 0) {
        int old = atomicAdd(tdone, 1);
        lastFlag = (old == (int)gridDim.x - 1) ? 1 : 0;
    }
    __syncthreads();
    if (lastFlag && tid < G) {
        int g = tid;
        float c = fmaxf(atomicAdd(&cnts[g], 0.f), 1.0f);
        float p0 = atomicAdd(&sums[2 * g], 0.f) / c;
        float p1 = atomicAdd(&sums[2 * g + 1], 0.f) / c;
        float m = fmaxf(p0, p1);
        float e0 = expf(p0 - m), e1 = expf(p1 - m);
        float inv = 1.f / (e0 + e1);
        out[2 * g] = e0 * inv;
        out[2 * g + 1] = e1 * inv;
    }
}

// ---------------------------------------------------------------------------
extern "C" void kernel_launch(void* const* d_in, const int* in_sizes, int n_in,
                              void* d_out, int out_size, void* d_ws, size_t ws_size,
                              hipStream_t stream) {
    const float* X   = (const float*)d_in[0];
    const int* EI    = (const int*)d_in[1];
    const int* BATCH = (const int*)d_in[2];
    const float* W1  = (const float*)d_in[3];
    const float* B1  = (const float*)d_in[4];
    const float* W2  = (const float*)d_in[5];
    const float* B2  = (const float*)d_in[6];
    const float* W3  = (const float*)d_in[7];
    const float* B3  = (const float*)d_in[8];
    const float* FW1 = (const float*)d_in[9];
    const float* FB1 = (const float*)d_in[10];
    const float* FW2 = (const float*)d_in[11];
    const float* FB2 = (const float*)d_in[12];

    const int N = in_sizes[0] / CH;
    const int E = in_sizes[1] / 2;
    const int G = out_size / 2;
    const int* rowp = EI;
    const int* colp = EI + E;
    const int NB = (N + 127) >> BSH;

    char* w = (char*)d_ws;
    auto alloc = [&](size_t bytes) -> char* {
        char* p = w;
        w += (bytes + 255) & ~(size_t)255;
        return p;
    };
    ucharT*  Z8    = (ucharT*)alloc((size_t)N * CH);        // fp8 Z (agg out)
    ucharT*  Hb8   = (ucharT*)alloc((size_t)N * CH);        // fp8 H1/H2
    ucharT*  Xb8   = (ucharT*)alloc((size_t)N * CH);        // fp8 X
    ushortT* WhiA  = (ushortT*)alloc((size_t)4 * 16384 * 2);
    float* invs    = (float*)alloc((size_t)N * 4);
    uintT* indptr  = (uintT*)alloc((size_t)N * 4);
    uintT* epack   = (uintT*)alloc((size_t)NB * SEGP * 4);
    uintT* seg     = (uintT*)alloc((size_t)NB * SEG * 4);
    int*   bfill   = (int*)alloc((size_t)NB * 4);
    float* sums    = (float*)alloc((size_t)G * 3 * 4);      // sums | cnts
    float* cnts    = sums + 2 * G;
    int*   tdone   = (int*)alloc(256);

    const int nbAgg  = (N + 31) / 32;
    const int nbGemm = (N + 127) / 128;
    const int nbBin  = (E + EPW - 1) / EPW;
    const int total4 = N * CH / 4;
    const int nbXc   = (total4 + 255) / 256;

    hipMemsetAsync(bfill, 0, (size_t)NB * 4, stream);
    k_bin<<<nbBin + 256 + nbXc, 256, 0, stream>>>(rowp, colp, bfill, seg,
                                                  X, Xb8, W1, W2, W3, FW1, WhiA,
                                                  sums, tdone, E, nbBin, NB, G, total4);
    k_binvs<<<NB, 512, 0, stream>>>(bfill, seg, invs, NB, N);
    k_scatter<<<NB, 256, 0, stream>>>(bfill, seg, invs, indptr, epack, N, NB);

    // layer 1
    k_agg<<<nbAgg, 256, 0, stream>>>(Xb8, epack, indptr, invs, Z8, N);
    k_gemm<<<nbGemm, 256, 0, stream>>>(Z8, WhiA, B1, Hb8, N);
    // layer 2
    k_agg<<<nbAgg, 256, 0, stream>>>(Hb8, epack, indptr, invs, Z8, N);
    k_gemm<<<nbGemm, 256, 0, stream>>>(Z8, WhiA + 16384, B2, Hb8, N);
    // layer 3 agg, then fused tail (GEMM W3 + FC1 + FC2 + pool + softmax)
    k_agg<<<nbAgg, 256, 0, stream>>>(Hb8, epack, indptr, invs, Z8, N);
    k_tail<<<nbGemm, 256, 0, stream>>>(Z8, WhiA + 2 * 16384, B3,
                                       WhiA + 3 * 16384, FB1, FW2, FB2,
                                       BATCH, sums, cnts, (float*)d_out, tdone, N, G);
}